// Round 1
// baseline (326.917 us; speedup 1.0000x reference)
//
#include <hip/hip_runtime.h>
#include <hip/hip_bf16.h>
#include <math.h>

typedef __attribute__((ext_vector_type(8))) short  short8;
typedef __attribute__((ext_vector_type(4))) float  f32x4;
typedef __attribute__((ext_vector_type(4))) unsigned short u16x4;
typedef __attribute__((ext_vector_type(8))) unsigned short u16x8;

#define BATCH 16384
#define NF    64
#define BAGL  10
#define ED    16
#define DW    1024   // F*E

static __device__ __forceinline__ unsigned short f2bf(float f) {
    unsigned int u = __builtin_bit_cast(unsigned int, f);
    unsigned int r = (u + 0x7fffu + ((u >> 16) & 1u)) >> 16;
    return (unsigned short)r;
}
static __device__ __forceinline__ float bf2f(unsigned short h) {
    unsigned int u = ((unsigned int)h) << 16;
    return __builtin_bit_cast(float, u);
}

// ---------------- 1. embedding gather + bag-sum, write bf16 x [B,1024] -----
__global__ __launch_bounds__(256) void pool_kernel(const int* __restrict__ idx,
                                                   const float* __restrict__ emb,
                                                   unsigned short* __restrict__ xb) {
    const int gid = blockIdx.x * 256 + threadIdx.x;   // B*F*4 threads
    const int bag = gid >> 2;                         // b*F + f
    const int q   = gid & 3;                          // which float4 of E=16
    const int* ip = idx + (long long)bag * BAGL;
    f32x4 acc = {0.f, 0.f, 0.f, 0.f};
#pragma unroll
    for (int l = 0; l < BAGL; ++l) {
        const int v = ip[l];
        const f32x4 e = *(const f32x4*)(emb + (((long long)v) << 4) + (q << 2));
        acc += e;
    }
    u16x4 o;
#pragma unroll
    for (int j = 0; j < 4; ++j) o[j] = f2bf(acc[j]);
    *(u16x4*)(xb + (((long long)bag) << 4) + (q << 2)) = o;
}

// ---------------- 2. per-column sum / sumsq over batch ---------------------
__global__ __launch_bounds__(256) void stats_kernel(const unsigned short* __restrict__ xb,
                                                    float* __restrict__ ssum,
                                                    float* __restrict__ ssq) {
    const int t = threadIdx.x;                 // cols 4t..4t+3
    const long long r0 = (long long)blockIdx.x * 128;
    float s[4] = {0, 0, 0, 0}, q[4] = {0, 0, 0, 0};
    for (int r = 0; r < 128; ++r) {
        const u16x4 v = *(const u16x4*)(xb + (r0 + r) * DW + t * 4);
#pragma unroll
        for (int j = 0; j < 4; ++j) { float f = bf2f(v[j]); s[j] += f; q[j] += f * f; }
    }
#pragma unroll
    for (int j = 0; j < 4; ++j) {
        atomicAdd(&ssum[t * 4 + j], s[j]);
        atomicAdd(&ssq [t * 4 + j], q[j]);
    }
}

__global__ void finalize_stats(const float* __restrict__ ssum, const float* __restrict__ ssq,
                               float* __restrict__ mean, float* __restrict__ rsig) {
    const int c = blockIdx.x * 256 + threadIdx.x;    // 1024 total
    const float m = ssum[c] * (1.0f / (float)BATCH);
    const float v = ssq[c] * (1.0f / (float)BATCH) - m * m;
    mean[c] = m;
    rsig[c] = rsqrtf(v + 1e-5f);
}

// ---------------- 3. normalize x in place ----------------------------------
__global__ __launch_bounds__(256) void normalize_kernel(unsigned short* __restrict__ xb,
                                                        const float* __restrict__ mean,
                                                        const float* __restrict__ rsig) {
    const long long gid = (long long)blockIdx.x * 256 + threadIdx.x;
    const long long off = gid * 8;
    const int c0 = (int)(off & (DW - 1));
    u16x8 v = *(u16x8*)(xb + off);
#pragma unroll
    for (int j = 0; j < 8; ++j) {
        float f = (bf2f(v[j]) - mean[c0 + j]) * rsig[c0 + j];
        v[j] = f2bf(f);
    }
    *(u16x8*)(xb + off) = v;
}

// ---------------- 4. W [R,C] f32 -> Wt [C,R] bf16 ---------------------------
__global__ __launch_bounds__(256) void transpose_f32_bf16(const float* __restrict__ src,
                                                          unsigned short* __restrict__ dst,
                                                          int R, int C) {
    __shared__ float tile[32][33];
    const int tx = threadIdx.x & 31, ty = threadIdx.x >> 5;
    const int bx = blockIdx.x, by = blockIdx.y;
#pragma unroll
    for (int i = 0; i < 4; ++i) {
        const int r = by * 32 + ty + i * 8, c = bx * 32 + tx;
        tile[ty + i * 8][tx] = src[(long long)r * C + c];
    }
    __syncthreads();
#pragma unroll
    for (int i = 0; i < 4; ++i) {
        const int oc = bx * 32 + ty + i * 8;     // column index -> row of dst
        dst[(long long)oc * R + by * 32 + tx] = f2bf(tile[tx][ty + i * 8]);
    }
}

// ---------------- 5. bf16 MFMA GEMM: C = act(A @ Bt^T + bias) --------------
// A [M,K] bf16 row-major, Bt [N,K] bf16 row-major, C [M,N] bf16, 128x128 tile
template <int RELU>
__global__ __launch_bounds__(256) void gemm_bt(const unsigned short* __restrict__ A,
                                               const unsigned short* __restrict__ Bt,
                                               const float* __restrict__ bias,
                                               unsigned short* __restrict__ C,
                                               int M, int N, int K) {
    __shared__ __align__(16) unsigned short As[128 * 32];
    __shared__ __align__(16) unsigned short Bs[128 * 32];
    const int tid = threadIdx.x;
    const int w = tid >> 6, l = tid & 63;
    const int wr = w >> 1, wc = w & 1;
    const int bm = blockIdx.x, bn = blockIdx.y;
    const int l15 = l & 15, l4 = l >> 4;

    f32x4 acc[4][4] = {};

    const long long a_base = (long long)bm * 128 * K;
    const long long b_base = (long long)bn * 128 * K;

    for (int k0 = 0; k0 < K; k0 += 32) {
#pragma unroll
        for (int i = 0; i < 2; ++i) {
            const int fl = i * 256 + tid;
            const int row = fl >> 2, kq = (fl & 3) << 3;
            __builtin_amdgcn_global_load_lds(
                (const __attribute__((address_space(1))) void*)(A + a_base + (long long)row * K + k0 + kq),
                (__attribute__((address_space(3))) void*)(&As[fl * 8]), 16, 0, 0);
            __builtin_amdgcn_global_load_lds(
                (const __attribute__((address_space(1))) void*)(Bt + b_base + (long long)row * K + k0 + kq),
                (__attribute__((address_space(3))) void*)(&Bs[fl * 8]), 16, 0, 0);
        }
        __syncthreads();

        short8 a[4], b[4];
#pragma unroll
        for (int m = 0; m < 4; ++m)
            a[m] = *(const short8*)(As + (wr * 64 + m * 16 + l15) * 32 + l4 * 8);
#pragma unroll
        for (int n = 0; n < 4; ++n)
            b[n] = *(const short8*)(Bs + (wc * 64 + n * 16 + l15) * 32 + l4 * 8);
#pragma unroll
        for (int m = 0; m < 4; ++m)
#pragma unroll
            for (int n = 0; n < 4; ++n)
                acc[m][n] = __builtin_amdgcn_mfma_f32_16x16x32_bf16(a[m], b[n], acc[m][n], 0, 0, 0);
        __syncthreads();
    }

#pragma unroll
    for (int m = 0; m < 4; ++m) {
        const int grow_base = bm * 128 + wr * 64 + m * 16 + l4 * 4;
#pragma unroll
        for (int n = 0; n < 4; ++n) {
            const int gcol = bn * 128 + wc * 64 + n * 16 + l15;
            const float bv = bias[gcol];
#pragma unroll
            for (int j = 0; j < 4; ++j) {
                float v = acc[m][n][j] + bv;
                if (RELU) v = fmaxf(v, 0.0f);
                C[(long long)(grow_base + j) * N + gcol] = f2bf(v);
            }
        }
    }
}

// ---------------- 6. final 512-dot + sigmoid -------------------------------
__global__ __launch_bounds__(256) void final_kernel(const unsigned short* __restrict__ h2,
                                                    const float* __restrict__ W3,
                                                    const float* __restrict__ b3,
                                                    float* __restrict__ out) {
    __shared__ float w3s[512];
    const int tid = threadIdx.x;
    w3s[tid] = W3[tid];
    w3s[tid + 256] = W3[tid + 256];
    __syncthreads();
    const int wv = tid >> 6, l = tid & 63;
    const long long row = (long long)blockIdx.x * 4 + wv;
    const u16x8 h = *(const u16x8*)(h2 + row * 512 + l * 8);
    float acc = 0.f;
#pragma unroll
    for (int j = 0; j < 8; ++j) acc += bf2f(h[j]) * w3s[l * 8 + j];
#pragma unroll
    for (int off = 32; off > 0; off >>= 1) acc += __shfl_xor(acc, off, 64);
    if (l == 0) out[row] = 1.0f / (1.0f + expf(-(acc + b3[0])));
}

// ---------------- host ------------------------------------------------------
extern "C" void kernel_launch(void* const* d_in, const int* in_sizes, int n_in,
                              void* d_out, int out_size, void* d_ws, size_t ws_size,
                              hipStream_t stream) {
    const int*   idx = (const int*)d_in[0];
    const float* emb = (const float*)d_in[1];
    const float* W1  = (const float*)d_in[2];
    const float* b1  = (const float*)d_in[3];
    const float* W2  = (const float*)d_in[4];
    const float* b2  = (const float*)d_in[5];
    const float* W3  = (const float*)d_in[6];
    const float* b3  = (const float*)d_in[7];
    float* out = (float*)d_out;

    char* ws = (char*)d_ws;
    unsigned short* xb  = (unsigned short*)ws; ws += (size_t)BATCH * DW * 2;
    unsigned short* h1  = (unsigned short*)ws; ws += (size_t)BATCH * DW * 2;
    unsigned short* h2  = (unsigned short*)ws; ws += (size_t)BATCH * 512 * 2;
    unsigned short* w1t = (unsigned short*)ws; ws += (size_t)1024 * 1024 * 2;
    unsigned short* w2t = (unsigned short*)ws; ws += (size_t)512 * 1024 * 2;
    float* ssum = (float*)ws; ws += 4096;
    float* ssq  = (float*)ws; ws += 4096;
    float* mean = (float*)ws; ws += 4096;
    float* rsig = (float*)ws; ws += 4096;

    hipMemsetAsync(ssum, 0, 8192, stream);   // ssum + ssq are contiguous

    pool_kernel<<<(BATCH * NF * 4) / 256, 256, 0, stream>>>(idx, emb, xb);
    stats_kernel<<<BATCH / 128, 256, 0, stream>>>(xb, ssum, ssq);
    finalize_stats<<<4, 256, 0, stream>>>(ssum, ssq, mean, rsig);
    normalize_kernel<<<(BATCH * DW / 8) / 256, 256, 0, stream>>>(xb, mean, rsig);

    transpose_f32_bf16<<<dim3(32, 32), 256, 0, stream>>>(W1, w1t, 1024, 1024);
    transpose_f32_bf16<<<dim3(16, 32), 256, 0, stream>>>(W2, w2t, 1024, 512);

    gemm_bt<1><<<dim3(BATCH / 128, 1024 / 128), 256, 0, stream>>>(xb, w1t, b1, h1, BATCH, 1024, 1024);
    gemm_bt<1><<<dim3(BATCH / 128, 512 / 128), 256, 0, stream>>>(h1, w2t, b2, h2, BATCH, 512, 1024);

    final_kernel<<<BATCH / 4, 256, 0, stream>>>(h2, W3, b3, out);
}